// Round 16
// baseline (544.477 us; speedup 1.0000x reference)
//
#include <hip/hip_runtime.h>

// PoissonPinn, round-19: LDS 33280 -> 32768 (SKE 256 + XOR swizzle) to lift
// the occupancy cap 3 -> 4-5 blocks/CU.
//
// R18 post-mortem: 549->513, VALU 233us + MFMA 200us + ~33 idle, still
// additive (phase-locked even across 3 blocks/SIMD). VGPR=84 since R16;
// LDS 33280 at 16K granule = 48K -> 3 blocks/CU = the binding resource,
// 512 B over the 32K line. SKE 260->256 = exactly 32768 -> 5 blocks by LDS.
// 512B rows need the XOR swizzle back: col' = col ^ (row<<2) on 8B blocks.
// Audit: loadB/storeP bank = (b^m) mod 16 all-distinct per 16-lane group;
// layer-0 write = exactly 4 lanes/bank-pair (wave64 minimum). Conflict-free.
//
// Kept from R18: cvt_pk packing, rcp-tanh, f32x2 pk epilogues, 16-MFMA
// chunks, bf16 weights, 3-deep A pipeline, own-chunk MFMAs, float4 bias
// loads, boundary blocks at grid front, (256,2).

constexpr int HID   = 256;
constexpr int MPTS  = 16;
constexpr int SKE   = 256;             // row stride elems (512 B) + XOR swizzle
constexpr int WELEM = 3 * HID * HID;
constexpr int HLSB  = 4 * MPTS * SKE * 2;   // 32768 B exactly

typedef __bf16 bf16x8 __attribute__((ext_vector_type(8)));
typedef __bf16 bf16x2 __attribute__((ext_vector_type(2)));
typedef float  f32x4  __attribute__((ext_vector_type(4)));
typedef float  f32x2  __attribute__((ext_vector_type(2)));
typedef unsigned int u32x4 __attribute__((ext_vector_type(4)));
typedef unsigned int u32x2 __attribute__((ext_vector_type(2)));

__device__ __forceinline__ float fast_tanh(float x) {
    const float e = __expf(2.0f * x);
    const float r = __builtin_amdgcn_rcpf(e + 1.0f);
    return fmaf(-2.0f, r, 1.0f);
}

// pair tanh: packed mul/add/fma, scalar v_exp / v_rcp
__device__ __forceinline__ f32x2 tanh2(f32x2 x) {
    const f32x2 t = x * 2.0f;
    f32x2 e;
    e[0] = __expf(t[0]);
    e[1] = __expf(t[1]);
    const f32x2 den = e + 1.0f;
    f32x2 r;
    r[0] = __builtin_amdgcn_rcpf(den[0]);
    r[1] = __builtin_amdgcn_rcpf(den[1]);
    return 1.0f - 2.0f * r;
}

// packed RNE bf16x2 (compiler emits v_cvt_pk_bf16_f32; x -> low16, y -> high16)
__device__ __forceinline__ unsigned cvtpk(float x, float y) {
    bf16x2 t;
    t[0] = (__bf16)x;
    t[1] = (__bf16)y;
    return __builtin_bit_cast(unsigned, t);
}

struct packed2 { unsigned hi, lo; };

// v-channel split: RNE hi + exact residual, both via cvt_pk
__device__ __forceinline__ packed2 packv(float x, float y) {
    packed2 r;
    r.hi = cvtpk(x, y);
    const f32x2 hf = {__uint_as_float(r.hi << 16),
                      __uint_as_float(r.hi & 0xFFFF0000u)};
    const f32x2 res = f32x2{x, y} - hf;
    r.lo = cvtpk(res[0], res[1]);
    return r;
}

// weights: RNE bf16 only
__global__ void prep_w(const float* __restrict__ W1,
                       const float* __restrict__ W2,
                       const float* __restrict__ W3,
                       __bf16* __restrict__ Wh) {
    const int idx = blockIdx.x * 256 + threadIdx.x;
    const int l   = idx >> 16;
    const int r   = idx & 0xFFFF;
    const int NT  = r >> 12;
    const int ks  = (r >> 9) & 7;
    const int ln  = (r >> 3) & 63;
    const int j   = r & 7;
    const int q   = ln >> 4;
    const int mm  = ln & 15;
    const int k   = ks * 32 + ((j >> 2) << 4) + q * 4 + (j & 3);
    const int n   = NT * 16 + mm;
    const float* W = (l == 0) ? W1 : (l == 1) ? W2 : W3;
    Wh[idx] = (__bf16)W[k * HID + n];
}

__global__ __launch_bounds__(256, 2)
void pinn_fused(const float* __restrict__ xe, const float* __restrict__ xb,
                const float* __restrict__ W0, const float* __restrict__ b0,
                const float* __restrict__ b1, const float* __restrict__ b2,
                const float* __restrict__ b3, const float* __restrict__ W4,
                const float* __restrict__ b4,
                const float* __restrict__ W1f, const float* __restrict__ W2f,
                const float* __restrict__ W3f,
                const __bf16* __restrict__ Wh,
                float* __restrict__ out, int nbb, int n_eq)
{
    __shared__ __align__(16) unsigned char smem[HLSB];

    const int tid  = threadIdx.x;
    const int lane = tid & 63;
    const int wv   = tid >> 6;

    if ((int)blockIdx.x < nbb) {
        // ======== boundary path (grid FRONT: overlaps the eq bulk) ========
        float (*HV)[HID] = (float (*)[HID])smem;     // 16 KB < 32 KB
        const int rbase = wv * 4;
        const int pbase = (int)blockIdx.x * 16 + rbase;
        float* bout = out + n_eq;

        #pragma unroll
        for (int c = 0; c < 4; ++c) {
            const int   j  = lane + 64 * c;
            const float w  = W0[j];
            const float bb = b0[j];
            #pragma unroll
            for (int p = 0; p < 4; ++p)
                HV[rbase + p][j] = fast_tanh(xb[pbase + p] * w + bb);
        }
        __syncthreads();

        const float* Ws[3] = {W1f, W2f, W3f};
        const float* bs[3] = {b1, b2, b3};

        #pragma unroll
        for (int l = 0; l < 3; ++l) {
            const float* __restrict__ W = Ws[l];
            const float* __restrict__ b = bs[l];

            float zv[4][4];
            #pragma unroll
            for (int p = 0; p < 4; ++p)
                #pragma unroll
                for (int c = 0; c < 4; ++c)
                    zv[p][c] = b[lane + 64 * c];

            for (int i = 0; i < HID; i += 4) {
                float w[4][4];
                #pragma unroll
                for (int qq = 0; qq < 4; ++qq)
                    #pragma unroll
                    for (int c = 0; c < 4; ++c)
                        w[qq][c] = W[(i + qq) * HID + lane + 64 * c];

                #pragma unroll
                for (int p = 0; p < 4; ++p) {
                    const float4 av = *(const float4*)&HV[rbase + p][i];
                    #pragma unroll
                    for (int qq = 0; qq < 4; ++qq) {
                        const float a_v = ((const float*)&av)[qq];
                        #pragma unroll
                        for (int c = 0; c < 4; ++c)
                            zv[p][c] = fmaf(a_v, w[qq][c], zv[p][c]);
                    }
                }
            }
            __syncthreads();

            #pragma unroll
            for (int p = 0; p < 4; ++p)
                #pragma unroll
                for (int c = 0; c < 4; ++c)
                    HV[rbase + p][lane + 64 * c] = fast_tanh(zv[p][c]);
            __syncthreads();
        }

        const float bias4 = b4[0];
        #pragma unroll
        for (int p = 0; p < 4; ++p) {
            float acc = 0.0f;
            #pragma unroll
            for (int c = 0; c < 4; ++c) {
                const int j = lane + 64 * c;
                acc = fmaf(HV[rbase + p][j], W4[j], acc);
            }
            #pragma unroll
            for (int off = 32; off > 0; off >>= 1)
                acc += __shfl_down(acc, off, 64);
            if (lane == 0) bout[pbase + p] = acc + bias4;
        }
        return;
    }

    // ================= equation path =================
    // LDS planes: 0 = v-hi, 1 = v-lo, 2 = d (bf16), 3 = s (bf16)
    // XOR swizzle on 8B blocks: element col' = col ^ (row<<2)
    typedef __bf16 (*HlsT)[MPTS][SKE];
    HlsT Hls = (HlsT)smem;                               // [4][16][256]
    float (*red)[16] = (float (*)[16])smem;              // aliases Hls (guarded)

    const int m    = lane & 15;
    const int q    = lane >> 4;
    const int pb   = ((int)blockIdx.x - nbb) * MPTS;

    f32x4 acc[3][4];                               // [ch][nt], nt = 2c+t
    bf16x8 AH[3][4];                               // 3-deep A pipeline (hi only)
    u32x4  B[2][4];                                // 2-deep B: [buf][plane]

    auto zacc = [&]() {
        #pragma unroll
        for (int ch = 0; ch < 3; ++ch)
            #pragma unroll
            for (int nt = 0; nt < 4; ++nt)
                acc[ch][nt] = (f32x4)0.0f;
    };
    auto loadA = [&](int ab, const __bf16* wh, int ks) {
        #pragma unroll
        for (int nt = 0; nt < 4; ++nt) {
            const int off = (((wv * 4 + nt) * 8 + ks) * 64 + lane) * 8;
            AH[ab][nt] = *(const bf16x8*)(wh + off);
        }
    };
    // b64 pairs, swizzled: bank = (blk ^ m) mod 16, distinct per 16-lane group
    auto loadB = [&](int bb, int ks) {
        const int sw  = m << 2;
        const int cb0 = (ks * 32 + q * 8) ^ sw;
        const int cb1 = (ks * 32 + q * 8 + 4) ^ sw;
        #pragma unroll
        for (int pl = 0; pl < 4; ++pl) {
            const u32x2 a  = *(const u32x2*)&Hls[pl][m][cb0];
            const u32x2 b2 = *(const u32x2*)&Hls[pl][m][cb1];
            B[bb][pl] = u32x4{a[0], a[1], b2[0], b2[1]};
        }
    };
    auto MF = [&](const bf16x8& a, const u32x4& b, const f32x4& c) {
        return __builtin_amdgcn_mfma_f32_16x16x32_bf16(
            a, __builtin_bit_cast(bf16x8, b), c, 0, 0, 0);
    };
    // 16 MFMAs/chunk: v = AhVh + AhVl (8), d = AhDh (4), s = AhSh (4)
    auto mfma16 = [&](int ab, int bb) {
        __builtin_amdgcn_s_setprio(1);
        #pragma unroll
        for (int nt = 0; nt < 4; ++nt) acc[0][nt] = MF(AH[ab][nt], B[bb][0], acc[0][nt]);
        #pragma unroll
        for (int nt = 0; nt < 4; ++nt) acc[1][nt] = MF(AH[ab][nt], B[bb][2], acc[1][nt]);
        #pragma unroll
        for (int nt = 0; nt < 4; ++nt) acc[2][nt] = MF(AH[ab][nt], B[bb][3], acc[2][nt]);
        #pragma unroll
        for (int nt = 0; nt < 4; ++nt) acc[0][nt] = MF(AH[ab][nt], B[bb][1], acc[0][nt]);
        __builtin_amdgcn_s_setprio(0);
    };
    auto mfma16P = [&](int ab, const u32x4& vh, const u32x4& vl,
                       const u32x4& dh, const u32x4& sh) {
        __builtin_amdgcn_s_setprio(1);
        #pragma unroll
        for (int nt = 0; nt < 4; ++nt) acc[0][nt] = MF(AH[ab][nt], vh, acc[0][nt]);
        #pragma unroll
        for (int nt = 0; nt < 4; ++nt) acc[1][nt] = MF(AH[ab][nt], dh, acc[1][nt]);
        #pragma unroll
        for (int nt = 0; nt < 4; ++nt) acc[2][nt] = MF(AH[ab][nt], sh, acc[2][nt]);
        #pragma unroll
        for (int nt = 0; nt < 4; ++nt) acc[0][nt] = MF(AH[ab][nt], vl, acc[0][nt]);
        __builtin_amdgcn_s_setprio(0);
    };

    // ---- issue layer-1 chunks 0..2 (L2 latency hides under layer 0) ----
    loadA(0, Wh, 0);
    loadA(1, Wh, 1);
    loadA(2, Wh, 2);

    // ---- layer 0 (packed pairs) ----
    {
        const int p  = tid & 15;
        const int cg = (tid >> 4) * 16;
        const int ks = cg >> 5;
        const int t  = (cg >> 4) & 1;
        const float xv = xe[pb + p];
        float4 w4[4], bq4[4];
        #pragma unroll
        for (int g = 0; g < 4; ++g) {
            w4[g]  = *(const float4*)&W0[cg + 4 * g];
            bq4[g] = *(const float4*)&b0[cg + 4 * g];
        }
        float vv[16], dd[16], ss[16];
        #pragma unroll
        for (int j = 0; j < 8; ++j) {             // pairs (2j, 2j+1)
            const f32x2 w  = {((const float*)&w4[j >> 1])[(j & 1) * 2],
                              ((const float*)&w4[j >> 1])[(j & 1) * 2 + 1]};
            const f32x2 bb = {((const float*)&bq4[j >> 1])[(j & 1) * 2],
                              ((const float*)&bq4[j >> 1])[(j & 1) * 2 + 1]};
            const f32x2 z  = w * xv + bb;
            const f32x2 v  = tanh2(z);
            const f32x2 s2 = 1.0f - v * v;
            const f32x2 d  = s2 * w;
            const f32x2 s  = -2.0f * ((v * s2) * (w * w));
            vv[2 * j] = v[0];  vv[2 * j + 1] = v[1];
            dd[2 * j] = d[0];  dd[2 * j + 1] = d[1];
            ss[2 * j] = s[0];  ss[2 * j + 1] = s[1];
        }
        #pragma unroll
        for (int g = 0; g < 4; ++g) {
            const int col = (32 * ks + 8 * g + 4 * t) ^ (p << 2);
            const packed2 p0 = packv(vv[g * 4 + 0], vv[g * 4 + 1]);
            const packed2 p1 = packv(vv[g * 4 + 2], vv[g * 4 + 3]);
            *(u32x2*)&Hls[0][p][col] = u32x2{p0.hi, p1.hi};
            *(u32x2*)&Hls[1][p][col] = u32x2{p0.lo, p1.lo};
            *(u32x2*)&Hls[2][p][col] = u32x2{cvtpk(dd[g * 4 + 0], dd[g * 4 + 1]),
                                             cvtpk(dd[g * 4 + 2], dd[g * 4 + 3])};
            *(u32x2*)&Hls[3][p][col] = u32x2{cvtpk(ss[g * 4 + 0], ss[g * 4 + 1]),
                                             cvtpk(ss[g * 4 + 2], ss[g * 4 + 3])};
        }
    }
    __syncthreads();

    // ---- layer 1 GEMM: 8 chunks, 3-deep A pipeline ----
    zacc();
    loadB(0, 0);
    #pragma unroll
    for (int it = 0; it < 8; ++it) {
        if (it + 1 < 8) loadB((it + 1) & 1, it + 1);
        mfma16(it % 3, it & 1);
        if (it + 3 < 8) loadA(it % 3, Wh, it + 3);
    }

    // ---- transitions ----
    #pragma unroll 1
    for (int l = 0; l < 2; ++l) {
        const __bf16* whN = Wh + (l + 1) * (HID * HID);
        const float* bl = (l == 0) ? b1 : b2;

        // bias vectors for this wave's 16 outputs: contiguous in r -> float4
        float4 bias4[2][2];
        #pragma unroll
        for (int c = 0; c < 2; ++c)
            #pragma unroll
            for (int t = 0; t < 2; ++t)
                bias4[c][t] = *(const float4*)&bl[64 * wv + 32 * c + 16 * t + 4 * q];

        __syncthreads();   // drain: all waves done reading H(l)
        loadA(0, whN, 2 * wv);                    // own chunk c=0
        loadA(1, whN, 2 * wv + 1);                // own chunk c=1

        u32x4 PVH[2], PVL[2], PD[2], PS[2];
        #pragma unroll
        for (int c = 0; c < 2; ++c)
            #pragma unroll
            for (int i = 0; i < 4; ++i) {
                const int t  = i >> 1;
                const int r0 = (i & 1) * 2;
                const int nt = c * 2 + t;
                const f32x2 bia = {((const float*)&bias4[c][t])[r0],
                                   ((const float*)&bias4[c][t])[r0 + 1]};
                const f32x2 zv  = f32x2{acc[0][nt][r0], acc[0][nt][r0 + 1]} + bia;
                const f32x2 zd  = {acc[1][nt][r0], acc[1][nt][r0 + 1]};
                const f32x2 zs  = {acc[2][nt][r0], acc[2][nt][r0 + 1]};
                const f32x2 v   = tanh2(zv);
                const f32x2 s2  = 1.0f - v * v;
                const f32x2 dn  = s2 * zd;
                const f32x2 sn  = s2 * zs - 2.0f * ((v * s2) * (zd * zd));
                const packed2 pv = packv(v[0], v[1]);
                PVH[c][i] = pv.hi;
                PVL[c][i] = pv.lo;
                PD[c][i]  = cvtpk(dn[0], dn[1]);
                PS[c][i]  = cvtpk(sn[0], sn[1]);
            }

        // exchange store: 16 b64 writes (swizzled, conflict-free), drain
        // under the own-chunk MFMAs below
        #pragma unroll
        for (int c = 0; c < 2; ++c) {
            const int sw  = m << 2;
            const int cb0 = ((2 * wv + c) * 32 + q * 8) ^ sw;
            const int cb1 = ((2 * wv + c) * 32 + q * 8 + 4) ^ sw;
            *(u32x2*)&Hls[0][m][cb0] = u32x2{PVH[c][0], PVH[c][1]};
            *(u32x2*)&Hls[0][m][cb1] = u32x2{PVH[c][2], PVH[c][3]};
            *(u32x2*)&Hls[1][m][cb0] = u32x2{PVL[c][0], PVL[c][1]};
            *(u32x2*)&Hls[1][m][cb1] = u32x2{PVL[c][2], PVL[c][3]};
            *(u32x2*)&Hls[2][m][cb0] = u32x2{PD[c][0], PD[c][1]};
            *(u32x2*)&Hls[2][m][cb1] = u32x2{PD[c][2], PD[c][3]};
            *(u32x2*)&Hls[3][m][cb0] = u32x2{PS[c][0], PS[c][1]};
            *(u32x2*)&Hls[3][m][cb1] = u32x2{PS[c][2], PS[c][3]};
        }

        zacc();
        mfma16P(0, PVH[0], PVL[0], PD[0], PS[0]);
        mfma16P(1, PVH[1], PVL[1], PD[1], PS[1]);

        loadA(2, whN, (2 * wv + 2) & 7);          // first LDS chunk
        __syncthreads();   // publish H(l+1)
        loadB(0, (2 * wv + 2) & 7);
        loadA(0, whN, (2 * wv + 3) & 7);
        loadA(1, whN, (2 * wv + 4) & 7);
        #pragma unroll
        for (int it = 0; it < 6; ++it) {
            if (it + 1 < 6) loadB((it + 1) & 1, (2 * wv + 3 + it) & 7);
            mfma16((2 + it) % 3, it & 1);
            if (it + 3 < 6) loadA((2 + it) % 3, whN, (2 * wv + 5 + it) & 7);
        }
    }

    // ---- layer 3 finish: s-channel register-direct into W4 dot (packed) ----
    {
        float4 b3v[4], w4v[4];
        #pragma unroll
        for (int nt = 0; nt < 4; ++nt) {
            b3v[nt] = *(const float4*)&b3[64 * wv + 16 * nt + 4 * q];
            w4v[nt] = *(const float4*)&W4[64 * wv + 16 * nt + 4 * q];
        }
        float P = 0.0f;
        #pragma unroll
        for (int nt = 0; nt < 4; ++nt)
            #pragma unroll
            for (int h = 0; h < 2; ++h) {
                const int r0 = h * 2;
                const f32x2 bia = {((const float*)&b3v[nt])[r0],
                                   ((const float*)&b3v[nt])[r0 + 1]};
                const f32x2 zv  = f32x2{acc[0][nt][r0], acc[0][nt][r0 + 1]} + bia;
                const f32x2 zd  = {acc[1][nt][r0], acc[1][nt][r0 + 1]};
                const f32x2 zs  = {acc[2][nt][r0], acc[2][nt][r0 + 1]};
                const f32x2 v   = tanh2(zv);
                const f32x2 s2  = 1.0f - v * v;
                const f32x2 sn  = s2 * zs - 2.0f * ((v * s2) * (zd * zd));
                P = fmaf(sn[0], ((const float*)&w4v[nt])[r0], P);
                P = fmaf(sn[1], ((const float*)&w4v[nt])[r0 + 1], P);
            }
        P += __shfl_xor(P, 16, 64);
        P += __shfl_xor(P, 32, 64);
        __syncthreads();   // all Hls reads done; red may alias Hls
        if (q == 0) red[wv][m] = P;
        __syncthreads();
        if (tid < 16)
            out[pb + tid] = red[0][tid] + red[1][tid] + red[2][tid] + red[3][tid];
    }
}

extern "C" void kernel_launch(void* const* d_in, const int* in_sizes, int n_in,
                              void* d_out, int out_size, void* d_ws, size_t ws_size,
                              hipStream_t stream) {
    const float* xe = (const float*)d_in[0];
    const float* xb = (const float*)d_in[1];
    const float* W0 = (const float*)d_in[2];
    const float* b0 = (const float*)d_in[3];
    const float* W1 = (const float*)d_in[4];
    const float* b1 = (const float*)d_in[5];
    const float* W2 = (const float*)d_in[6];
    const float* b2 = (const float*)d_in[7];
    const float* W3 = (const float*)d_in[8];
    const float* b3 = (const float*)d_in[9];
    const float* W4 = (const float*)d_in[10];
    const float* b4 = (const float*)d_in[11];
    float* out = (float*)d_out;

    const int n_eq = in_sizes[0];   // 262144
    const int n_b  = in_sizes[1];   // 8192

    __bf16* Wh = (__bf16*)d_ws;

    const int neqb = n_eq / MPTS;                  // 16384
    const int nbb  = n_b / 16;                     // 512

    prep_w<<<WELEM / 256, 256, 0, stream>>>(W1, W2, W3, Wh);

    pinn_fused<<<neqb + nbb, 256, 0, stream>>>(
        xe, xb, W0, b0, b1, b2, b3, W4, b4, W1, W2, W3, Wh, out, nbb, n_eq);
}

// Round 17
// 522.952 us; speedup vs baseline: 1.0412x; 1.0412x over previous
//
#include <hip/hip_runtime.h>

// PoissonPinn, round-20: revert R19 (swizzle/SKE256 cost VALU, occupancy
// counter unreliable) back to the proven R18 config; + exp2-argument folding
// for the tanh chain.
//
// R19 post-mortem: smaller LDS -> LOWER measured occupancy and +31us; the
// XOR swizzle added a VALU op per LDS access on a VALU-bound kernel.
// RULE: judge by dur + work terms only; don't buy occupancy with VALU.
//
// R20 trim: tanh(z) = 1 - 2/(exp2(K z)+1), K = 2 log2 e. K folds into the
// existing FMA chain (transitions: t = acc*K + bias*K replaces add+mul+2 muls;
// layer-0: xvK = xv*K once). Raw v_exp via __builtin_amdgcn_exp2f
// (__has_builtin-guarded, exp2f fallback). ~64 slots/thread + shorter dep
// chain. Limits preserved; rounding change << bf16 storage error.
//
// Kept (R18 config): SKE=260 no swizzle (0 conflicts), cvt_pk packing,
// rcp-tanh, f32x2 pk epilogues, 16-MFMA chunks, bf16 weights, 3-deep A
// pipeline, own-chunk MFMAs, float4 bias loads, boundary at grid front,
// (256,2).

constexpr int HID   = 256;
constexpr int MPTS  = 16;
constexpr int SKE   = 260;             // row stride elems (520 B, odd x 8B)
constexpr int WELEM = 3 * HID * HID;
constexpr int HLSB  = 4 * MPTS * SKE * 2;   // 33280 B

typedef __bf16 bf16x8 __attribute__((ext_vector_type(8)));
typedef __bf16 bf16x2 __attribute__((ext_vector_type(2)));
typedef float  f32x4  __attribute__((ext_vector_type(4)));
typedef float  f32x2  __attribute__((ext_vector_type(2)));
typedef unsigned int u32x4 __attribute__((ext_vector_type(4)));
typedef unsigned int u32x2 __attribute__((ext_vector_type(2)));

#define KK 2.8853900817779268f    /* 2*log2(e) */

#if __has_builtin(__builtin_amdgcn_exp2f)
#define EXP2R(x) __builtin_amdgcn_exp2f(x)
#else
#define EXP2R(x) exp2f(x)
#endif

__device__ __forceinline__ float fast_tanh(float x) {
    const float e = __expf(2.0f * x);
    const float r = __builtin_amdgcn_rcpf(e + 1.0f);
    return fmaf(-2.0f, r, 1.0f);
}

// pair tanh from pre-scaled argument t = K*z (so exp2(t) = exp(2z))
__device__ __forceinline__ f32x2 tanh2t(f32x2 t) {
    f32x2 e;
    e[0] = EXP2R(t[0]);
    e[1] = EXP2R(t[1]);
    const f32x2 den = e + 1.0f;
    f32x2 r;
    r[0] = __builtin_amdgcn_rcpf(den[0]);
    r[1] = __builtin_amdgcn_rcpf(den[1]);
    return 1.0f - 2.0f * r;
}

// packed RNE bf16x2 (compiler emits v_cvt_pk_bf16_f32; x -> low16, y -> high16)
__device__ __forceinline__ unsigned cvtpk(float x, float y) {
    bf16x2 t;
    t[0] = (__bf16)x;
    t[1] = (__bf16)y;
    return __builtin_bit_cast(unsigned, t);
}

struct packed2 { unsigned hi, lo; };

// v-channel split: RNE hi + exact residual, both via cvt_pk
__device__ __forceinline__ packed2 packv(float x, float y) {
    packed2 r;
    r.hi = cvtpk(x, y);
    const f32x2 hf = {__uint_as_float(r.hi << 16),
                      __uint_as_float(r.hi & 0xFFFF0000u)};
    const f32x2 res = f32x2{x, y} - hf;
    r.lo = cvtpk(res[0], res[1]);
    return r;
}

// weights: RNE bf16 only
__global__ void prep_w(const float* __restrict__ W1,
                       const float* __restrict__ W2,
                       const float* __restrict__ W3,
                       __bf16* __restrict__ Wh) {
    const int idx = blockIdx.x * 256 + threadIdx.x;
    const int l   = idx >> 16;
    const int r   = idx & 0xFFFF;
    const int NT  = r >> 12;
    const int ks  = (r >> 9) & 7;
    const int ln  = (r >> 3) & 63;
    const int j   = r & 7;
    const int q   = ln >> 4;
    const int mm  = ln & 15;
    const int k   = ks * 32 + ((j >> 2) << 4) + q * 4 + (j & 3);
    const int n   = NT * 16 + mm;
    const float* W = (l == 0) ? W1 : (l == 1) ? W2 : W3;
    Wh[idx] = (__bf16)W[k * HID + n];
}

__global__ __launch_bounds__(256, 2)
void pinn_fused(const float* __restrict__ xe, const float* __restrict__ xb,
                const float* __restrict__ W0, const float* __restrict__ b0,
                const float* __restrict__ b1, const float* __restrict__ b2,
                const float* __restrict__ b3, const float* __restrict__ W4,
                const float* __restrict__ b4,
                const float* __restrict__ W1f, const float* __restrict__ W2f,
                const float* __restrict__ W3f,
                const __bf16* __restrict__ Wh,
                float* __restrict__ out, int nbb, int n_eq)
{
    __shared__ __align__(16) unsigned char smem[HLSB];

    const int tid  = threadIdx.x;
    const int lane = tid & 63;
    const int wv   = tid >> 6;

    if ((int)blockIdx.x < nbb) {
        // ======== boundary path (grid FRONT: overlaps the eq bulk) ========
        float (*HV)[HID] = (float (*)[HID])smem;     // 16 KB < 33 KB
        const int rbase = wv * 4;
        const int pbase = (int)blockIdx.x * 16 + rbase;
        float* bout = out + n_eq;

        #pragma unroll
        for (int c = 0; c < 4; ++c) {
            const int   j  = lane + 64 * c;
            const float w  = W0[j];
            const float bb = b0[j];
            #pragma unroll
            for (int p = 0; p < 4; ++p)
                HV[rbase + p][j] = fast_tanh(xb[pbase + p] * w + bb);
        }
        __syncthreads();

        const float* Ws[3] = {W1f, W2f, W3f};
        const float* bs[3] = {b1, b2, b3};

        #pragma unroll
        for (int l = 0; l < 3; ++l) {
            const float* __restrict__ W = Ws[l];
            const float* __restrict__ b = bs[l];

            float zv[4][4];
            #pragma unroll
            for (int p = 0; p < 4; ++p)
                #pragma unroll
                for (int c = 0; c < 4; ++c)
                    zv[p][c] = b[lane + 64 * c];

            for (int i = 0; i < HID; i += 4) {
                float w[4][4];
                #pragma unroll
                for (int qq = 0; qq < 4; ++qq)
                    #pragma unroll
                    for (int c = 0; c < 4; ++c)
                        w[qq][c] = W[(i + qq) * HID + lane + 64 * c];

                #pragma unroll
                for (int p = 0; p < 4; ++p) {
                    const float4 av = *(const float4*)&HV[rbase + p][i];
                    #pragma unroll
                    for (int qq = 0; qq < 4; ++qq) {
                        const float a_v = ((const float*)&av)[qq];
                        #pragma unroll
                        for (int c = 0; c < 4; ++c)
                            zv[p][c] = fmaf(a_v, w[qq][c], zv[p][c]);
                    }
                }
            }
            __syncthreads();

            #pragma unroll
            for (int p = 0; p < 4; ++p)
                #pragma unroll
                for (int c = 0; c < 4; ++c)
                    HV[rbase + p][lane + 64 * c] = fast_tanh(zv[p][c]);
            __syncthreads();
        }

        const float bias4 = b4[0];
        #pragma unroll
        for (int p = 0; p < 4; ++p) {
            float acc = 0.0f;
            #pragma unroll
            for (int c = 0; c < 4; ++c) {
                const int j = lane + 64 * c;
                acc = fmaf(HV[rbase + p][j], W4[j], acc);
            }
            #pragma unroll
            for (int off = 32; off > 0; off >>= 1)
                acc += __shfl_down(acc, off, 64);
            if (lane == 0) bout[pbase + p] = acc + bias4;
        }
        return;
    }

    // ================= equation path =================
    // LDS planes: 0 = v-hi, 1 = v-lo, 2 = d (bf16), 3 = s (bf16)
    typedef __bf16 (*HlsT)[MPTS][SKE];
    HlsT Hls = (HlsT)smem;                               // [4][16][260]
    float (*red)[16] = (float (*)[16])smem;              // aliases Hls (guarded)

    const int m    = lane & 15;
    const int q    = lane >> 4;
    const int pb   = ((int)blockIdx.x - nbb) * MPTS;

    f32x4 acc[3][4];                               // [ch][nt], nt = 2c+t
    bf16x8 AH[3][4];                               // 3-deep A pipeline (hi only)
    u32x4  B[2][4];                                // 2-deep B: [buf][plane]

    auto zacc = [&]() {
        #pragma unroll
        for (int ch = 0; ch < 3; ++ch)
            #pragma unroll
            for (int nt = 0; nt < 4; ++nt)
                acc[ch][nt] = (f32x4)0.0f;
    };
    auto loadA = [&](int ab, const __bf16* wh, int ks) {
        #pragma unroll
        for (int nt = 0; nt < 4; ++nt) {
            const int off = (((wv * 4 + nt) * 8 + ks) * 64 + lane) * 8;
            AH[ab][nt] = *(const bf16x8*)(wh + off);
        }
    };
    // b64 pairs, conflict-free map (R12/R13, measured 0 conflicts)
    auto loadB = [&](int bb, int ks) {
        const int cb = ks * 32 + q * 8;
        #pragma unroll
        for (int pl = 0; pl < 4; ++pl) {
            const u32x2 a  = *(const u32x2*)&Hls[pl][m][cb];
            const u32x2 b2 = *(const u32x2*)&Hls[pl][m][cb + 4];
            B[bb][pl] = u32x4{a[0], a[1], b2[0], b2[1]};
        }
    };
    auto MF = [&](const bf16x8& a, const u32x4& b, const f32x4& c) {
        return __builtin_amdgcn_mfma_f32_16x16x32_bf16(
            a, __builtin_bit_cast(bf16x8, b), c, 0, 0, 0);
    };
    // 16 MFMAs/chunk: v = AhVh + AhVl (8), d = AhDh (4), s = AhSh (4)
    auto mfma16 = [&](int ab, int bb) {
        __builtin_amdgcn_s_setprio(1);
        #pragma unroll
        for (int nt = 0; nt < 4; ++nt) acc[0][nt] = MF(AH[ab][nt], B[bb][0], acc[0][nt]);
        #pragma unroll
        for (int nt = 0; nt < 4; ++nt) acc[1][nt] = MF(AH[ab][nt], B[bb][2], acc[1][nt]);
        #pragma unroll
        for (int nt = 0; nt < 4; ++nt) acc[2][nt] = MF(AH[ab][nt], B[bb][3], acc[2][nt]);
        #pragma unroll
        for (int nt = 0; nt < 4; ++nt) acc[0][nt] = MF(AH[ab][nt], B[bb][1], acc[0][nt]);
        __builtin_amdgcn_s_setprio(0);
    };
    auto mfma16P = [&](int ab, const u32x4& vh, const u32x4& vl,
                       const u32x4& dh, const u32x4& sh) {
        __builtin_amdgcn_s_setprio(1);
        #pragma unroll
        for (int nt = 0; nt < 4; ++nt) acc[0][nt] = MF(AH[ab][nt], vh, acc[0][nt]);
        #pragma unroll
        for (int nt = 0; nt < 4; ++nt) acc[1][nt] = MF(AH[ab][nt], dh, acc[1][nt]);
        #pragma unroll
        for (int nt = 0; nt < 4; ++nt) acc[2][nt] = MF(AH[ab][nt], sh, acc[2][nt]);
        #pragma unroll
        for (int nt = 0; nt < 4; ++nt) acc[0][nt] = MF(AH[ab][nt], vl, acc[0][nt]);
        __builtin_amdgcn_s_setprio(0);
    };

    // ---- issue layer-1 chunks 0..2 (L2 latency hides under layer 0) ----
    loadA(0, Wh, 0);
    loadA(1, Wh, 1);
    loadA(2, Wh, 2);

    // ---- layer 0 (packed pairs, exp2-folded tanh) ----
    {
        const int p  = tid & 15;
        const int cg = (tid >> 4) * 16;
        const int ks = cg >> 5;
        const int t  = (cg >> 4) & 1;
        const float xv  = xe[pb + p];
        const float xvK = xv * KK;
        float4 w4[4], bq4[4];
        #pragma unroll
        for (int g = 0; g < 4; ++g) {
            w4[g]  = *(const float4*)&W0[cg + 4 * g];
            bq4[g] = *(const float4*)&b0[cg + 4 * g];
        }
        float vv[16], dd[16], ss[16];
        #pragma unroll
        for (int j = 0; j < 8; ++j) {             // pairs (2j, 2j+1)
            const f32x2 w  = {((const float*)&w4[j >> 1])[(j & 1) * 2],
                              ((const float*)&w4[j >> 1])[(j & 1) * 2 + 1]};
            const f32x2 bb = {((const float*)&bq4[j >> 1])[(j & 1) * 2],
                              ((const float*)&bq4[j >> 1])[(j & 1) * 2 + 1]};
            const f32x2 tK = w * xvK + bb * KK;   // = K*(w*xv + b)
            const f32x2 v  = tanh2t(tK);
            const f32x2 s2 = 1.0f - v * v;
            const f32x2 d  = s2 * w;
            const f32x2 s  = -2.0f * ((v * s2) * (w * w));
            vv[2 * j] = v[0];  vv[2 * j + 1] = v[1];
            dd[2 * j] = d[0];  dd[2 * j + 1] = d[1];
            ss[2 * j] = s[0];  ss[2 * j + 1] = s[1];
        }
        #pragma unroll
        for (int g = 0; g < 4; ++g) {
            const int col = 32 * ks + 8 * g + 4 * t;
            const packed2 p0 = packv(vv[g * 4 + 0], vv[g * 4 + 1]);
            const packed2 p1 = packv(vv[g * 4 + 2], vv[g * 4 + 3]);
            *(u32x2*)&Hls[0][p][col] = u32x2{p0.hi, p1.hi};
            *(u32x2*)&Hls[1][p][col] = u32x2{p0.lo, p1.lo};
            *(u32x2*)&Hls[2][p][col] = u32x2{cvtpk(dd[g * 4 + 0], dd[g * 4 + 1]),
                                             cvtpk(dd[g * 4 + 2], dd[g * 4 + 3])};
            *(u32x2*)&Hls[3][p][col] = u32x2{cvtpk(ss[g * 4 + 0], ss[g * 4 + 1]),
                                             cvtpk(ss[g * 4 + 2], ss[g * 4 + 3])};
        }
    }
    __syncthreads();

    // ---- layer 1 GEMM: 8 chunks, 3-deep A pipeline ----
    zacc();
    loadB(0, 0);
    #pragma unroll
    for (int it = 0; it < 8; ++it) {
        if (it + 1 < 8) loadB((it + 1) & 1, it + 1);
        mfma16(it % 3, it & 1);
        if (it + 3 < 8) loadA(it % 3, Wh, it + 3);
    }

    // ---- transitions ----
    #pragma unroll 1
    for (int l = 0; l < 2; ++l) {
        const __bf16* whN = Wh + (l + 1) * (HID * HID);
        const float* bl = (l == 0) ? b1 : b2;

        // bias vectors for this wave's 16 outputs: contiguous in r -> float4
        float4 bias4[2][2];
        #pragma unroll
        for (int c = 0; c < 2; ++c)
            #pragma unroll
            for (int t = 0; t < 2; ++t)
                bias4[c][t] = *(const float4*)&bl[64 * wv + 32 * c + 16 * t + 4 * q];

        __syncthreads();   // drain: all waves done reading H(l)
        loadA(0, whN, 2 * wv);                    // own chunk c=0
        loadA(1, whN, 2 * wv + 1);                // own chunk c=1

        u32x4 PVH[2], PVL[2], PD[2], PS[2];
        #pragma unroll
        for (int c = 0; c < 2; ++c)
            #pragma unroll
            for (int i = 0; i < 4; ++i) {
                const int t  = i >> 1;
                const int r0 = (i & 1) * 2;
                const int nt = c * 2 + t;
                const f32x2 bia = {((const float*)&bias4[c][t])[r0],
                                   ((const float*)&bias4[c][t])[r0 + 1]};
                const f32x2 zd  = {acc[1][nt][r0], acc[1][nt][r0 + 1]};
                const f32x2 zs  = {acc[2][nt][r0], acc[2][nt][r0 + 1]};
                const f32x2 tK  = f32x2{acc[0][nt][r0], acc[0][nt][r0 + 1]} * KK
                                  + bia * KK;     // = K*(acc + bias)
                const f32x2 v   = tanh2t(tK);
                const f32x2 s2  = 1.0f - v * v;
                const f32x2 dn  = s2 * zd;
                const f32x2 sn  = s2 * zs - 2.0f * ((v * s2) * (zd * zd));
                const packed2 pv = packv(v[0], v[1]);
                PVH[c][i] = pv.hi;
                PVL[c][i] = pv.lo;
                PD[c][i]  = cvtpk(dn[0], dn[1]);
                PS[c][i]  = cvtpk(sn[0], sn[1]);
            }

        // exchange store: 16 b64 writes (conflict-free), drain under own MFMAs
        #pragma unroll
        for (int c = 0; c < 2; ++c) {
            const int cb = (2 * wv + c) * 32 + q * 8;
            *(u32x2*)&Hls[0][m][cb]     = u32x2{PVH[c][0], PVH[c][1]};
            *(u32x2*)&Hls[0][m][cb + 4] = u32x2{PVH[c][2], PVH[c][3]};
            *(u32x2*)&Hls[1][m][cb]     = u32x2{PVL[c][0], PVL[c][1]};
            *(u32x2*)&Hls[1][m][cb + 4] = u32x2{PVL[c][2], PVL[c][3]};
            *(u32x2*)&Hls[2][m][cb]     = u32x2{PD[c][0], PD[c][1]};
            *(u32x2*)&Hls[2][m][cb + 4] = u32x2{PD[c][2], PD[c][3]};
            *(u32x2*)&Hls[3][m][cb]     = u32x2{PS[c][0], PS[c][1]};
            *(u32x2*)&Hls[3][m][cb + 4] = u32x2{PS[c][2], PS[c][3]};
        }

        zacc();
        mfma16P(0, PVH[0], PVL[0], PD[0], PS[0]);
        mfma16P(1, PVH[1], PVL[1], PD[1], PS[1]);

        loadA(2, whN, (2 * wv + 2) & 7);          // first LDS chunk
        __syncthreads();   // publish H(l+1)
        loadB(0, (2 * wv + 2) & 7);
        loadA(0, whN, (2 * wv + 3) & 7);
        loadA(1, whN, (2 * wv + 4) & 7);
        #pragma unroll
        for (int it = 0; it < 6; ++it) {
            if (it + 1 < 6) loadB((it + 1) & 1, (2 * wv + 3 + it) & 7);
            mfma16((2 + it) % 3, it & 1);
            if (it + 3 < 6) loadA((2 + it) % 3, whN, (2 * wv + 5 + it) & 7);
        }
    }

    // ---- layer 3 finish: s-channel register-direct into W4 dot (packed) ----
    {
        float4 b3v[4], w4v[4];
        #pragma unroll
        for (int nt = 0; nt < 4; ++nt) {
            b3v[nt] = *(const float4*)&b3[64 * wv + 16 * nt + 4 * q];
            w4v[nt] = *(const float4*)&W4[64 * wv + 16 * nt + 4 * q];
        }
        float P = 0.0f;
        #pragma unroll
        for (int nt = 0; nt < 4; ++nt)
            #pragma unroll
            for (int h = 0; h < 2; ++h) {
                const int r0 = h * 2;
                const f32x2 bia = {((const float*)&b3v[nt])[r0],
                                   ((const float*)&b3v[nt])[r0 + 1]};
                const f32x2 zd  = {acc[1][nt][r0], acc[1][nt][r0 + 1]};
                const f32x2 zs  = {acc[2][nt][r0], acc[2][nt][r0 + 1]};
                const f32x2 tK  = f32x2{acc[0][nt][r0], acc[0][nt][r0 + 1]} * KK
                                  + bia * KK;
                const f32x2 v   = tanh2t(tK);
                const f32x2 s2  = 1.0f - v * v;
                const f32x2 sn  = s2 * zs - 2.0f * ((v * s2) * (zd * zd));
                P = fmaf(sn[0], ((const float*)&w4v[nt])[r0], P);
                P = fmaf(sn[1], ((const float*)&w4v[nt])[r0 + 1], P);
            }
        P += __shfl_xor(P, 16, 64);
        P += __shfl_xor(P, 32, 64);
        __syncthreads();   // all Hls reads done; red may alias Hls
        if (q == 0) red[wv][m] = P;
        __syncthreads();
        if (tid < 16)
            out[pb + tid] = red[0][tid] + red[1][tid] + red[2][tid] + red[3][tid];
    }
}

extern "C" void kernel_launch(void* const* d_in, const int* in_sizes, int n_in,
                              void* d_out, int out_size, void* d_ws, size_t ws_size,
                              hipStream_t stream) {
    const float* xe = (const float*)d_in[0];
    const float* xb = (const float*)d_in[1];
    const float* W0 = (const float*)d_in[2];
    const float* b0 = (const float*)d_in[3];
    const float* W1 = (const float*)d_in[4];
    const float* b1 = (const float*)d_in[5];
    const float* W2 = (const float*)d_in[6];
    const float* b2 = (const float*)d_in[7];
    const float* W3 = (const float*)d_in[8];
    const float* b3 = (const float*)d_in[9];
    const float* W4 = (const float*)d_in[10];
    const float* b4 = (const float*)d_in[11];
    float* out = (float*)d_out;

    const int n_eq = in_sizes[0];   // 262144
    const int n_b  = in_sizes[1];   // 8192

    __bf16* Wh = (__bf16*)d_ws;

    const int neqb = n_eq / MPTS;                  // 16384
    const int nbb  = n_b / 16;                     // 512

    prep_w<<<WELEM / 256, 256, 0, stream>>>(W1, W2, W3, Wh);

    pinn_fused<<<neqb + nbb, 256, 0, stream>>>(
        xe, xb, W0, b0, b1, b2, b3, W4, b4, W1, W2, W3, Wh, out, nbb, n_eq);
}

// Round 18
// 512.047 us; speedup vs baseline: 1.0633x; 1.0213x over previous
//
#include <hip/hip_runtime.h>

// PoissonPinn, round-21: exact revert to the measured optimum (R18, 512.7us).
//
// R20 post-mortem: exp2-arg folding regressed ~10us — equal issue slots but a
// LONGER serial dep chain ahead of each v_exp; at ~2.7 waves/SIMD the added
// latency isn't hidden (idle 33->49us). Second consecutive micro-edit inside
// the noise/latency band (R19: swizzle/occupancy trade, -31us).
//
// Terminal state analysis: MFMA 200us = exact algorithmic floor at verified
// precision (v 2-term, d/s 1-term bf16; v-lo removal would breach 8.5e-4);
// VALU ~226us after 4 diet rounds (div->rcp, pk-f32, cvt_pk, float4 loads);
// idle ~35us barrier drain. MfmaUtil+VALUBusy ~90%, additive — six overlap
// attempts (interleave/stagger/deep-prefetch/occupancy x2/swizzle) all null
// or negative. Remaining ideas are measured losses or correctness risks.
// => lock in the proven-best configuration.
//
// Config (R18): SKE=260 no swizzle (0 conflicts), cvt_pk packing, rcp-tanh,
// f32x2 pk epilogues, 16-MFMA chunks (v=AhVh+AhVl, d=AhDh, s=AhSh), bf16
// weights, 3-deep A pipeline, own-chunk register-direct MFMAs, float4 bias
// loads, boundary blocks at grid front, (256,2).

constexpr int HID   = 256;
constexpr int MPTS  = 16;
constexpr int SKE   = 260;             // row stride elems (520 B, odd x 8B)
constexpr int WELEM = 3 * HID * HID;
constexpr int HLSB  = 4 * MPTS * SKE * 2;   // 33280 B

typedef __bf16 bf16x8 __attribute__((ext_vector_type(8)));
typedef __bf16 bf16x2 __attribute__((ext_vector_type(2)));
typedef float  f32x4  __attribute__((ext_vector_type(4)));
typedef float  f32x2  __attribute__((ext_vector_type(2)));
typedef unsigned int u32x4 __attribute__((ext_vector_type(4)));
typedef unsigned int u32x2 __attribute__((ext_vector_type(2)));

__device__ __forceinline__ float fast_tanh(float x) {
    const float e = __expf(2.0f * x);
    const float r = __builtin_amdgcn_rcpf(e + 1.0f);
    return fmaf(-2.0f, r, 1.0f);
}

// pair tanh: packed mul/add/fma, scalar v_exp / v_rcp
__device__ __forceinline__ f32x2 tanh2(f32x2 x) {
    const f32x2 t = x * 2.0f;
    f32x2 e;
    e[0] = __expf(t[0]);
    e[1] = __expf(t[1]);
    const f32x2 den = e + 1.0f;
    f32x2 r;
    r[0] = __builtin_amdgcn_rcpf(den[0]);
    r[1] = __builtin_amdgcn_rcpf(den[1]);
    return 1.0f - 2.0f * r;
}

// packed RNE bf16x2 (compiler emits v_cvt_pk_bf16_f32; x -> low16, y -> high16)
__device__ __forceinline__ unsigned cvtpk(float x, float y) {
    bf16x2 t;
    t[0] = (__bf16)x;
    t[1] = (__bf16)y;
    return __builtin_bit_cast(unsigned, t);
}

struct packed2 { unsigned hi, lo; };

// v-channel split: RNE hi + exact residual, both via cvt_pk
__device__ __forceinline__ packed2 packv(float x, float y) {
    packed2 r;
    r.hi = cvtpk(x, y);
    const f32x2 hf = {__uint_as_float(r.hi << 16),
                      __uint_as_float(r.hi & 0xFFFF0000u)};
    const f32x2 res = f32x2{x, y} - hf;
    r.lo = cvtpk(res[0], res[1]);
    return r;
}

// weights: RNE bf16 only
__global__ void prep_w(const float* __restrict__ W1,
                       const float* __restrict__ W2,
                       const float* __restrict__ W3,
                       __bf16* __restrict__ Wh) {
    const int idx = blockIdx.x * 256 + threadIdx.x;
    const int l   = idx >> 16;
    const int r   = idx & 0xFFFF;
    const int NT  = r >> 12;
    const int ks  = (r >> 9) & 7;
    const int ln  = (r >> 3) & 63;
    const int j   = r & 7;
    const int q   = ln >> 4;
    const int mm  = ln & 15;
    const int k   = ks * 32 + ((j >> 2) << 4) + q * 4 + (j & 3);
    const int n   = NT * 16 + mm;
    const float* W = (l == 0) ? W1 : (l == 1) ? W2 : W3;
    Wh[idx] = (__bf16)W[k * HID + n];
}

__global__ __launch_bounds__(256, 2)
void pinn_fused(const float* __restrict__ xe, const float* __restrict__ xb,
                const float* __restrict__ W0, const float* __restrict__ b0,
                const float* __restrict__ b1, const float* __restrict__ b2,
                const float* __restrict__ b3, const float* __restrict__ W4,
                const float* __restrict__ b4,
                const float* __restrict__ W1f, const float* __restrict__ W2f,
                const float* __restrict__ W3f,
                const __bf16* __restrict__ Wh,
                float* __restrict__ out, int nbb, int n_eq)
{
    __shared__ __align__(16) unsigned char smem[HLSB];

    const int tid  = threadIdx.x;
    const int lane = tid & 63;
    const int wv   = tid >> 6;

    if ((int)blockIdx.x < nbb) {
        // ======== boundary path (grid FRONT: overlaps the eq bulk) ========
        float (*HV)[HID] = (float (*)[HID])smem;     // 16 KB < 33 KB
        const int rbase = wv * 4;
        const int pbase = (int)blockIdx.x * 16 + rbase;
        float* bout = out + n_eq;

        #pragma unroll
        for (int c = 0; c < 4; ++c) {
            const int   j  = lane + 64 * c;
            const float w  = W0[j];
            const float bb = b0[j];
            #pragma unroll
            for (int p = 0; p < 4; ++p)
                HV[rbase + p][j] = fast_tanh(xb[pbase + p] * w + bb);
        }
        __syncthreads();

        const float* Ws[3] = {W1f, W2f, W3f};
        const float* bs[3] = {b1, b2, b3};

        #pragma unroll
        for (int l = 0; l < 3; ++l) {
            const float* __restrict__ W = Ws[l];
            const float* __restrict__ b = bs[l];

            float zv[4][4];
            #pragma unroll
            for (int p = 0; p < 4; ++p)
                #pragma unroll
                for (int c = 0; c < 4; ++c)
                    zv[p][c] = b[lane + 64 * c];

            for (int i = 0; i < HID; i += 4) {
                float w[4][4];
                #pragma unroll
                for (int qq = 0; qq < 4; ++qq)
                    #pragma unroll
                    for (int c = 0; c < 4; ++c)
                        w[qq][c] = W[(i + qq) * HID + lane + 64 * c];

                #pragma unroll
                for (int p = 0; p < 4; ++p) {
                    const float4 av = *(const float4*)&HV[rbase + p][i];
                    #pragma unroll
                    for (int qq = 0; qq < 4; ++qq) {
                        const float a_v = ((const float*)&av)[qq];
                        #pragma unroll
                        for (int c = 0; c < 4; ++c)
                            zv[p][c] = fmaf(a_v, w[qq][c], zv[p][c]);
                    }
                }
            }
            __syncthreads();

            #pragma unroll
            for (int p = 0; p < 4; ++p)
                #pragma unroll
                for (int c = 0; c < 4; ++c)
                    HV[rbase + p][lane + 64 * c] = fast_tanh(zv[p][c]);
            __syncthreads();
        }

        const float bias4 = b4[0];
        #pragma unroll
        for (int p = 0; p < 4; ++p) {
            float acc = 0.0f;
            #pragma unroll
            for (int c = 0; c < 4; ++c) {
                const int j = lane + 64 * c;
                acc = fmaf(HV[rbase + p][j], W4[j], acc);
            }
            #pragma unroll
            for (int off = 32; off > 0; off >>= 1)
                acc += __shfl_down(acc, off, 64);
            if (lane == 0) bout[pbase + p] = acc + bias4;
        }
        return;
    }

    // ================= equation path =================
    // LDS planes: 0 = v-hi, 1 = v-lo, 2 = d (bf16), 3 = s (bf16)
    typedef __bf16 (*HlsT)[MPTS][SKE];
    HlsT Hls = (HlsT)smem;                               // [4][16][260]
    float (*red)[16] = (float (*)[16])smem;              // aliases Hls (guarded)

    const int m    = lane & 15;
    const int q    = lane >> 4;
    const int pb   = ((int)blockIdx.x - nbb) * MPTS;

    f32x4 acc[3][4];                               // [ch][nt], nt = 2c+t
    bf16x8 AH[3][4];                               // 3-deep A pipeline (hi only)
    u32x4  B[2][4];                                // 2-deep B: [buf][plane]

    auto zacc = [&]() {
        #pragma unroll
        for (int ch = 0; ch < 3; ++ch)
            #pragma unroll
            for (int nt = 0; nt < 4; ++nt)
                acc[ch][nt] = (f32x4)0.0f;
    };
    auto loadA = [&](int ab, const __bf16* wh, int ks) {
        #pragma unroll
        for (int nt = 0; nt < 4; ++nt) {
            const int off = (((wv * 4 + nt) * 8 + ks) * 64 + lane) * 8;
            AH[ab][nt] = *(const bf16x8*)(wh + off);
        }
    };
    // b64 pairs, conflict-free map (R12/R13, measured 0 conflicts)
    auto loadB = [&](int bb, int ks) {
        const int cb = ks * 32 + q * 8;
        #pragma unroll
        for (int pl = 0; pl < 4; ++pl) {
            const u32x2 a  = *(const u32x2*)&Hls[pl][m][cb];
            const u32x2 b2 = *(const u32x2*)&Hls[pl][m][cb + 4];
            B[bb][pl] = u32x4{a[0], a[1], b2[0], b2[1]};
        }
    };
    auto MF = [&](const bf16x8& a, const u32x4& b, const f32x4& c) {
        return __builtin_amdgcn_mfma_f32_16x16x32_bf16(
            a, __builtin_bit_cast(bf16x8, b), c, 0, 0, 0);
    };
    // 16 MFMAs/chunk: v = AhVh + AhVl (8), d = AhDh (4), s = AhSh (4)
    auto mfma16 = [&](int ab, int bb) {
        __builtin_amdgcn_s_setprio(1);
        #pragma unroll
        for (int nt = 0; nt < 4; ++nt) acc[0][nt] = MF(AH[ab][nt], B[bb][0], acc[0][nt]);
        #pragma unroll
        for (int nt = 0; nt < 4; ++nt) acc[1][nt] = MF(AH[ab][nt], B[bb][2], acc[1][nt]);
        #pragma unroll
        for (int nt = 0; nt < 4; ++nt) acc[2][nt] = MF(AH[ab][nt], B[bb][3], acc[2][nt]);
        #pragma unroll
        for (int nt = 0; nt < 4; ++nt) acc[0][nt] = MF(AH[ab][nt], B[bb][1], acc[0][nt]);
        __builtin_amdgcn_s_setprio(0);
    };
    auto mfma16P = [&](int ab, const u32x4& vh, const u32x4& vl,
                       const u32x4& dh, const u32x4& sh) {
        __builtin_amdgcn_s_setprio(1);
        #pragma unroll
        for (int nt = 0; nt < 4; ++nt) acc[0][nt] = MF(AH[ab][nt], vh, acc[0][nt]);
        #pragma unroll
        for (int nt = 0; nt < 4; ++nt) acc[1][nt] = MF(AH[ab][nt], dh, acc[1][nt]);
        #pragma unroll
        for (int nt = 0; nt < 4; ++nt) acc[2][nt] = MF(AH[ab][nt], sh, acc[2][nt]);
        #pragma unroll
        for (int nt = 0; nt < 4; ++nt) acc[0][nt] = MF(AH[ab][nt], vl, acc[0][nt]);
        __builtin_amdgcn_s_setprio(0);
    };

    // ---- issue layer-1 chunks 0..2 (L2 latency hides under layer 0) ----
    loadA(0, Wh, 0);
    loadA(1, Wh, 1);
    loadA(2, Wh, 2);

    // ---- layer 0 (packed pairs) ----
    {
        const int p  = tid & 15;
        const int cg = (tid >> 4) * 16;
        const int ks = cg >> 5;
        const int t  = (cg >> 4) & 1;
        const float xv = xe[pb + p];
        float4 w4[4], bq4[4];
        #pragma unroll
        for (int g = 0; g < 4; ++g) {
            w4[g]  = *(const float4*)&W0[cg + 4 * g];
            bq4[g] = *(const float4*)&b0[cg + 4 * g];
        }
        float vv[16], dd[16], ss[16];
        #pragma unroll
        for (int j = 0; j < 8; ++j) {             // pairs (2j, 2j+1)
            const f32x2 w  = {((const float*)&w4[j >> 1])[(j & 1) * 2],
                              ((const float*)&w4[j >> 1])[(j & 1) * 2 + 1]};
            const f32x2 bb = {((const float*)&bq4[j >> 1])[(j & 1) * 2],
                              ((const float*)&bq4[j >> 1])[(j & 1) * 2 + 1]};
            const f32x2 z  = w * xv + bb;
            const f32x2 v  = tanh2(z);
            const f32x2 s2 = 1.0f - v * v;
            const f32x2 d  = s2 * w;
            const f32x2 s  = -2.0f * ((v * s2) * (w * w));
            vv[2 * j] = v[0];  vv[2 * j + 1] = v[1];
            dd[2 * j] = d[0];  dd[2 * j + 1] = d[1];
            ss[2 * j] = s[0];  ss[2 * j + 1] = s[1];
        }
        #pragma unroll
        for (int g = 0; g < 4; ++g) {
            const int col = 32 * ks + 8 * g + 4 * t;
            const packed2 p0 = packv(vv[g * 4 + 0], vv[g * 4 + 1]);
            const packed2 p1 = packv(vv[g * 4 + 2], vv[g * 4 + 3]);
            *(u32x2*)&Hls[0][p][col] = u32x2{p0.hi, p1.hi};
            *(u32x2*)&Hls[1][p][col] = u32x2{p0.lo, p1.lo};
            *(u32x2*)&Hls[2][p][col] = u32x2{cvtpk(dd[g * 4 + 0], dd[g * 4 + 1]),
                                             cvtpk(dd[g * 4 + 2], dd[g * 4 + 3])};
            *(u32x2*)&Hls[3][p][col] = u32x2{cvtpk(ss[g * 4 + 0], ss[g * 4 + 1]),
                                             cvtpk(ss[g * 4 + 2], ss[g * 4 + 3])};
        }
    }
    __syncthreads();

    // ---- layer 1 GEMM: 8 chunks, 3-deep A pipeline ----
    zacc();
    loadB(0, 0);
    #pragma unroll
    for (int it = 0; it < 8; ++it) {
        if (it + 1 < 8) loadB((it + 1) & 1, it + 1);
        mfma16(it % 3, it & 1);
        if (it + 3 < 8) loadA(it % 3, Wh, it + 3);
    }

    // ---- transitions ----
    #pragma unroll 1
    for (int l = 0; l < 2; ++l) {
        const __bf16* whN = Wh + (l + 1) * (HID * HID);
        const float* bl = (l == 0) ? b1 : b2;

        // bias vectors for this wave's 16 outputs: contiguous in r -> float4
        float4 bias4[2][2];
        #pragma unroll
        for (int c = 0; c < 2; ++c)
            #pragma unroll
            for (int t = 0; t < 2; ++t)
                bias4[c][t] = *(const float4*)&bl[64 * wv + 32 * c + 16 * t + 4 * q];

        __syncthreads();   // drain: all waves done reading H(l)
        loadA(0, whN, 2 * wv);                    // own chunk c=0
        loadA(1, whN, 2 * wv + 1);                // own chunk c=1

        u32x4 PVH[2], PVL[2], PD[2], PS[2];
        #pragma unroll
        for (int c = 0; c < 2; ++c)
            #pragma unroll
            for (int i = 0; i < 4; ++i) {
                const int t  = i >> 1;
                const int r0 = (i & 1) * 2;
                const int nt = c * 2 + t;
                const f32x2 bia = {((const float*)&bias4[c][t])[r0],
                                   ((const float*)&bias4[c][t])[r0 + 1]};
                const f32x2 zv  = f32x2{acc[0][nt][r0], acc[0][nt][r0 + 1]} + bia;
                const f32x2 zd  = {acc[1][nt][r0], acc[1][nt][r0 + 1]};
                const f32x2 zs  = {acc[2][nt][r0], acc[2][nt][r0 + 1]};
                const f32x2 v   = tanh2(zv);
                const f32x2 s2  = 1.0f - v * v;
                const f32x2 dn  = s2 * zd;
                const f32x2 sn  = s2 * zs - 2.0f * ((v * s2) * (zd * zd));
                const packed2 pv = packv(v[0], v[1]);
                PVH[c][i] = pv.hi;
                PVL[c][i] = pv.lo;
                PD[c][i]  = cvtpk(dn[0], dn[1]);
                PS[c][i]  = cvtpk(sn[0], sn[1]);
            }

        // exchange store: 16 b64 writes (conflict-free), drain under own MFMAs
        #pragma unroll
        for (int c = 0; c < 2; ++c) {
            const int cb = (2 * wv + c) * 32 + q * 8;
            *(u32x2*)&Hls[0][m][cb]     = u32x2{PVH[c][0], PVH[c][1]};
            *(u32x2*)&Hls[0][m][cb + 4] = u32x2{PVH[c][2], PVH[c][3]};
            *(u32x2*)&Hls[1][m][cb]     = u32x2{PVL[c][0], PVL[c][1]};
            *(u32x2*)&Hls[1][m][cb + 4] = u32x2{PVL[c][2], PVL[c][3]};
            *(u32x2*)&Hls[2][m][cb]     = u32x2{PD[c][0], PD[c][1]};
            *(u32x2*)&Hls[2][m][cb + 4] = u32x2{PD[c][2], PD[c][3]};
            *(u32x2*)&Hls[3][m][cb]     = u32x2{PS[c][0], PS[c][1]};
            *(u32x2*)&Hls[3][m][cb + 4] = u32x2{PS[c][2], PS[c][3]};
        }

        zacc();
        mfma16P(0, PVH[0], PVL[0], PD[0], PS[0]);
        mfma16P(1, PVH[1], PVL[1], PD[1], PS[1]);

        loadA(2, whN, (2 * wv + 2) & 7);          // first LDS chunk
        __syncthreads();   // publish H(l+1)
        loadB(0, (2 * wv + 2) & 7);
        loadA(0, whN, (2 * wv + 3) & 7);
        loadA(1, whN, (2 * wv + 4) & 7);
        #pragma unroll
        for (int it = 0; it < 6; ++it) {
            if (it + 1 < 6) loadB((it + 1) & 1, (2 * wv + 3 + it) & 7);
            mfma16((2 + it) % 3, it & 1);
            if (it + 3 < 6) loadA((2 + it) % 3, whN, (2 * wv + 5 + it) & 7);
        }
    }

    // ---- layer 3 finish: s-channel register-direct into W4 dot (packed) ----
    {
        float4 b3v[4], w4v[4];
        #pragma unroll
        for (int nt = 0; nt < 4; ++nt) {
            b3v[nt] = *(const float4*)&b3[64 * wv + 16 * nt + 4 * q];
            w4v[nt] = *(const float4*)&W4[64 * wv + 16 * nt + 4 * q];
        }
        float P = 0.0f;
        #pragma unroll
        for (int nt = 0; nt < 4; ++nt)
            #pragma unroll
            for (int h = 0; h < 2; ++h) {
                const int r0 = h * 2;
                const f32x2 bia = {((const float*)&b3v[nt])[r0],
                                   ((const float*)&b3v[nt])[r0 + 1]};
                const f32x2 zv  = f32x2{acc[0][nt][r0], acc[0][nt][r0 + 1]} + bia;
                const f32x2 zd  = {acc[1][nt][r0], acc[1][nt][r0 + 1]};
                const f32x2 zs  = {acc[2][nt][r0], acc[2][nt][r0 + 1]};
                const f32x2 v   = tanh2(zv);
                const f32x2 s2  = 1.0f - v * v;
                const f32x2 sn  = s2 * zs - 2.0f * ((v * s2) * (zd * zd));
                P = fmaf(sn[0], ((const float*)&w4v[nt])[r0], P);
                P = fmaf(sn[1], ((const float*)&w4v[nt])[r0 + 1], P);
            }
        P += __shfl_xor(P, 16, 64);
        P += __shfl_xor(P, 32, 64);
        __syncthreads();   // all Hls reads done; red may alias Hls
        if (q == 0) red[wv][m] = P;
        __syncthreads();
        if (tid < 16)
            out[pb + tid] = red[0][tid] + red[1][tid] + red[2][tid] + red[3][tid];
    }
}

extern "C" void kernel_launch(void* const* d_in, const int* in_sizes, int n_in,
                              void* d_out, int out_size, void* d_ws, size_t ws_size,
                              hipStream_t stream) {
    const float* xe = (const float*)d_in[0];
    const float* xb = (const float*)d_in[1];
    const float* W0 = (const float*)d_in[2];
    const float* b0 = (const float*)d_in[3];
    const float* W1 = (const float*)d_in[4];
    const float* b1 = (const float*)d_in[5];
    const float* W2 = (const float*)d_in[6];
    const float* b2 = (const float*)d_in[7];
    const float* W3 = (const float*)d_in[8];
    const float* b3 = (const float*)d_in[9];
    const float* W4 = (const float*)d_in[10];
    const float* b4 = (const float*)d_in[11];
    float* out = (float*)d_out;

    const int n_eq = in_sizes[0];   // 262144
    const int n_b  = in_sizes[1];   // 8192

    __bf16* Wh = (__bf16*)d_ws;

    const int neqb = n_eq / MPTS;                  // 16384
    const int nbb  = n_b / 16;                     // 512

    prep_w<<<WELEM / 256, 256, 0, stream>>>(W1, W2, W3, Wh);

    pinn_fused<<<neqb + nbb, 256, 0, stream>>>(
        xe, xb, W0, b0, b1, b2, b3, W4, b4, W1, W2, W3, Wh, out, nbb, n_eq);
}